// Round 1
// baseline (10890.334 us; speedup 1.0000x reference)
//
#include <hip/hip_runtime.h>

#define NNODES 100000
#define F 256
#define NEDGES 3200000

// ---------------- Kernel 1: out[i][j] = b[j] ----------------
__global__ __launch_bounds__(256) void init_bias(float* __restrict__ out,
                                                 const float* __restrict__ b,
                                                 int total4) {
    int idx = blockIdx.x * blockDim.x + threadIdx.x;
    if (idx >= total4) return;
    int j4 = idx & (F / 4 - 1);               // F/4 = 64, power of 2
    float4 bv = ((const float4*)b)[j4];
    ((float4*)out)[idx] = bv;
}

// ---------------- Kernel 2: Y = X @ W^T  (fp32 SGEMM) ----------------
// X: [NNODES, F] row-major, W: [F, F] row-major (out_f, in_f), Y: [NNODES, F]
// Tile: BM=64 rows x BN=64 cols, BK=16. 256 threads, 4x4 microtile each.
#define BM 64
#define BN 64
#define BK 16
#define LDSS 68   // padded stride: 2-way bank aliasing only (free), keeps 16B alignment

__global__ __launch_bounds__(256) void gemm_xwt(const float* __restrict__ X,
                                                const float* __restrict__ W,
                                                float* __restrict__ Y) {
    __shared__ float As[BK][LDSS];   // k-major: As[k][row]
    __shared__ float Bs[BK][LDSS];   // k-major: Bs[k][col]

    const int tile_m = blockIdx.x;          // 0..1562
    const int tile_n = blockIdx.y;          // 0..3
    const int t  = threadIdx.x;
    const int tx = t & 15;                  // col group
    const int ty = t >> 4;                  // row group
    const int row_l = t >> 2;               // 0..63  (loader row within tile)
    const int kk4   = t & 3;                // 0..3   (which float4 along k)

    const int grow = tile_m * BM + row_l;   // global X row for loading
    const int gcol = tile_n * BN + row_l;   // global W row for loading (always < 256)

    float acc[4][4];
#pragma unroll
    for (int i = 0; i < 4; ++i)
#pragma unroll
        for (int j = 0; j < 4; ++j) acc[i][j] = 0.f;

    for (int k0 = 0; k0 < F; k0 += BK) {
        float4 a = make_float4(0.f, 0.f, 0.f, 0.f);
        if (grow < NNODES) a = *(const float4*)&X[(size_t)grow * F + k0 + kk4 * 4];
        float4 bv = *(const float4*)&W[(size_t)gcol * F + k0 + kk4 * 4];

        __syncthreads();   // protect previous iteration's LDS reads
        As[kk4 * 4 + 0][row_l] = a.x;
        As[kk4 * 4 + 1][row_l] = a.y;
        As[kk4 * 4 + 2][row_l] = a.z;
        As[kk4 * 4 + 3][row_l] = a.w;
        Bs[kk4 * 4 + 0][row_l] = bv.x;
        Bs[kk4 * 4 + 1][row_l] = bv.y;
        Bs[kk4 * 4 + 2][row_l] = bv.z;
        Bs[kk4 * 4 + 3][row_l] = bv.w;
        __syncthreads();

#pragma unroll
        for (int kk = 0; kk < BK; ++kk) {
            float4 av = *(const float4*)&As[kk][4 * ty];
            float4 bw = *(const float4*)&Bs[kk][4 * tx];
            const float aa[4] = {av.x, av.y, av.z, av.w};
            const float bb[4] = {bw.x, bw.y, bw.z, bw.w};
#pragma unroll
            for (int i = 0; i < 4; ++i)
#pragma unroll
                for (int j = 0; j < 4; ++j) acc[i][j] += aa[i] * bb[j];
        }
    }

#pragma unroll
    for (int i = 0; i < 4; ++i) {
        int orow = tile_m * BM + 4 * ty + i;
        if (orow < NNODES) {
            float4 o = make_float4(acc[i][0], acc[i][1], acc[i][2], acc[i][3]);
            *(float4*)&Y[(size_t)orow * F + tile_n * BN + 4 * tx] = o;
        }
    }
}

// ---------------- Kernel 3: out[src] += val * Y[dst] ----------------
// One wave (64 lanes) per edge; each lane owns 4 contiguous features.
__global__ __launch_bounds__(256) void scatter_edges(const int* __restrict__ src,
                                                     const int* __restrict__ dst,
                                                     const float* __restrict__ val,
                                                     const float* __restrict__ Y,
                                                     float* __restrict__ out,
                                                     int n_edges) {
    int e = blockIdx.x * 4 + (threadIdx.x >> 6);
    if (e >= n_edges) return;
    int lane = threadIdx.x & 63;
    int s = src[e];
    int d = dst[e];
    float v = val[e];
    float4 y = *(const float4*)&Y[(size_t)d * F + lane * 4];
    float* o = &out[(size_t)s * F + lane * 4];
    atomicAdd(o + 0, v * y.x);
    atomicAdd(o + 1, v * y.y);
    atomicAdd(o + 2, v * y.z);
    atomicAdd(o + 3, v * y.w);
}

extern "C" void kernel_launch(void* const* d_in, const int* in_sizes, int n_in,
                              void* d_out, int out_size, void* d_ws, size_t ws_size,
                              hipStream_t stream) {
    const float* X        = (const float*)d_in[0];
    const int*   edge_src = (const int*)d_in[1];
    const int*   edge_dst = (const int*)d_in[2];
    const float* edge_val = (const float*)d_in[3];
    const float* W        = (const float*)d_in[4];
    const float* b        = (const float*)d_in[5];
    float*       out      = (float*)d_out;
    float*       Y        = (float*)d_ws;          // NNODES*F fp32 = 102.4 MB
    const int n_edges     = in_sizes[1];

    // 1) out = broadcast(b)
    int total4 = NNODES * F / 4;
    init_bias<<<(total4 + 255) / 256, 256, 0, stream>>>(out, b, total4);

    // 2) Y = X @ W^T
    dim3 ggrid((NNODES + BM - 1) / BM, F / BN);
    gemm_xwt<<<ggrid, 256, 0, stream>>>(X, W, Y);

    // 3) out[src] += val * Y[dst]
    int eblocks = (n_edges + 3) / 4;
    scatter_edges<<<eblocks, 256, 0, stream>>>(edge_src, edge_dst, edge_val, Y, out, n_edges);
}

// Round 2
// 1244.122 us; speedup vs baseline: 8.7534x; 8.7534x over previous
//
#include <hip/hip_runtime.h>

#define NNODES 100000
#define F 256

// ---------------- GEMM: Y = X @ W^T  (fp32) ----------------
#define BM 64
#define BN 64
#define BK 16
#define LDSS 68

__global__ __launch_bounds__(256) void gemm_xwt(const float* __restrict__ X,
                                                const float* __restrict__ W,
                                                float* __restrict__ Y) {
    __shared__ float As[BK][LDSS];
    __shared__ float Bs[BK][LDSS];

    const int tile_m = blockIdx.x;
    const int tile_n = blockIdx.y;
    const int t  = threadIdx.x;
    const int tx = t & 15;
    const int ty = t >> 4;
    const int row_l = t >> 2;
    const int kk4   = t & 3;

    const int grow = tile_m * BM + row_l;
    const int gcol = tile_n * BN + row_l;

    float acc[4][4];
#pragma unroll
    for (int i = 0; i < 4; ++i)
#pragma unroll
        for (int j = 0; j < 4; ++j) acc[i][j] = 0.f;

    for (int k0 = 0; k0 < F; k0 += BK) {
        float4 a = make_float4(0.f, 0.f, 0.f, 0.f);
        if (grow < NNODES) a = *(const float4*)&X[(size_t)grow * F + k0 + kk4 * 4];
        float4 bv = *(const float4*)&W[(size_t)gcol * F + k0 + kk4 * 4];

        __syncthreads();
        As[kk4 * 4 + 0][row_l] = a.x;
        As[kk4 * 4 + 1][row_l] = a.y;
        As[kk4 * 4 + 2][row_l] = a.z;
        As[kk4 * 4 + 3][row_l] = a.w;
        Bs[kk4 * 4 + 0][row_l] = bv.x;
        Bs[kk4 * 4 + 1][row_l] = bv.y;
        Bs[kk4 * 4 + 2][row_l] = bv.z;
        Bs[kk4 * 4 + 3][row_l] = bv.w;
        __syncthreads();

#pragma unroll
        for (int kk = 0; kk < BK; ++kk) {
            float4 av = *(const float4*)&As[kk][4 * ty];
            float4 bw = *(const float4*)&Bs[kk][4 * tx];
            const float aa[4] = {av.x, av.y, av.z, av.w};
            const float bb[4] = {bw.x, bw.y, bw.z, bw.w};
#pragma unroll
            for (int i = 0; i < 4; ++i)
#pragma unroll
                for (int j = 0; j < 4; ++j) acc[i][j] += aa[i] * bb[j];
        }
    }

#pragma unroll
    for (int i = 0; i < 4; ++i) {
        int orow = tile_m * BM + 4 * ty + i;
        if (orow < NNODES) {
            float4 o = make_float4(acc[i][0], acc[i][1], acc[i][2], acc[i][3]);
            *(float4*)&Y[(size_t)orow * F + tile_n * BN + 4 * tx] = o;
        }
    }
}

// ---------------- CSR build ----------------
__global__ __launch_bounds__(256) void zero_int(int* __restrict__ p, int n) {
    int i = blockIdx.x * blockDim.x + threadIdx.x;
    if (i < n) p[i] = 0;
}

__global__ __launch_bounds__(256) void hist_src(const int* __restrict__ src,
                                                int* __restrict__ deg, int n_edges) {
    int e = blockIdx.x * blockDim.x + threadIdx.x;
    if (e < n_edges) atomicAdd(&deg[src[e]], 1);
}

// Single-block exclusive scan over NNODES degrees (wave-shuffle based).
__global__ __launch_bounds__(1024) void exscan_deg(const int* __restrict__ deg,
                                                   int* __restrict__ offs) {
    __shared__ int wsum[16];
    __shared__ int s_carry;
    const int lane = threadIdx.x & 63;
    const int wid  = threadIdx.x >> 6;
    if (threadIdx.x == 0) s_carry = 0;
    __syncthreads();

    for (int base = 0; base < NNODES; base += 1024) {
        int i = base + threadIdx.x;
        int v = (i < NNODES) ? deg[i] : 0;
        // inclusive wave scan
        int x = v;
#pragma unroll
        for (int off = 1; off < 64; off <<= 1) {
            int t = __shfl_up(x, off, 64);
            if (lane >= off) x += t;
        }
        if (lane == 63) wsum[wid] = x;
        __syncthreads();
        if (wid == 0 && lane < 16) {
            int y = wsum[lane];
            int z = y;
#pragma unroll
            for (int off = 1; off < 16; off <<= 1) {
                int t = __shfl_up(z, off, 64);
                if (lane >= off) z += t;
            }
            wsum[lane] = z - y;   // exclusive prefix of wave sums
        }
        __syncthreads();
        if (i < NNODES) offs[i] = s_carry + wsum[wid] + (x - v);
        __syncthreads();
        if (threadIdx.x == 1023) s_carry += wsum[15] + x;  // chunk total
        __syncthreads();
    }
    if (threadIdx.x == 0) offs[NNODES] = s_carry;
}

__global__ __launch_bounds__(256) void copy_offs(const int* __restrict__ offs,
                                                 int* __restrict__ cursor, int n) {
    int i = blockIdx.x * blockDim.x + threadIdx.x;
    if (i < n) cursor[i] = offs[i];
}

__global__ __launch_bounds__(256) void reorder_edges(const int* __restrict__ src,
                                                     const int* __restrict__ dst,
                                                     const float* __restrict__ val,
                                                     int* __restrict__ cursor,
                                                     int2* __restrict__ pack,
                                                     int n_edges) {
    int e = blockIdx.x * blockDim.x + threadIdx.x;
    if (e >= n_edges) return;
    int s = src[e];
    int pos = atomicAdd(&cursor[s], 1);
    pack[pos] = make_int2(dst[e], __float_as_int(val[e]));
}

// ---------------- Gather: out[node] = b + sum val * Y[dst] ----------------
// One wave per node; lane owns 4 contiguous features.
__global__ __launch_bounds__(256) void gather_nodes(const int* __restrict__ offs,
                                                    const int2* __restrict__ pack,
                                                    const float* __restrict__ Y,
                                                    const float* __restrict__ b,
                                                    float* __restrict__ out) {
    int node = blockIdx.x * 4 + (threadIdx.x >> 6);
    if (node >= NNODES) return;
    const int lane = threadIdx.x & 63;
    const int beg = offs[node];
    const int end = offs[node + 1];

    float4 acc = ((const float4*)b)[lane];

    int j = beg;
    for (; j + 3 < end; j += 4) {
        int2 p0 = pack[j + 0];
        int2 p1 = pack[j + 1];
        int2 p2 = pack[j + 2];
        int2 p3 = pack[j + 3];
        float4 y0 = *(const float4*)&Y[(size_t)p0.x * F + lane * 4];
        float4 y1 = *(const float4*)&Y[(size_t)p1.x * F + lane * 4];
        float4 y2 = *(const float4*)&Y[(size_t)p2.x * F + lane * 4];
        float4 y3 = *(const float4*)&Y[(size_t)p3.x * F + lane * 4];
        float v0 = __int_as_float(p0.y), v1 = __int_as_float(p1.y);
        float v2 = __int_as_float(p2.y), v3 = __int_as_float(p3.y);
        acc.x += v0 * y0.x; acc.y += v0 * y0.y; acc.z += v0 * y0.z; acc.w += v0 * y0.w;
        acc.x += v1 * y1.x; acc.y += v1 * y1.y; acc.z += v1 * y1.z; acc.w += v1 * y1.w;
        acc.x += v2 * y2.x; acc.y += v2 * y2.y; acc.z += v2 * y2.z; acc.w += v2 * y2.w;
        acc.x += v3 * y3.x; acc.y += v3 * y3.y; acc.z += v3 * y3.z; acc.w += v3 * y3.w;
    }
    for (; j < end; ++j) {
        int2 p = pack[j];
        float4 y = *(const float4*)&Y[(size_t)p.x * F + lane * 4];
        float v = __int_as_float(p.y);
        acc.x += v * y.x; acc.y += v * y.y; acc.z += v * y.z; acc.w += v * y.w;
    }

    *(float4*)&out[(size_t)node * F + lane * 4] = acc;
}

// ---------------- Fallback (R1 atomic path) ----------------
__global__ __launch_bounds__(256) void init_bias(float* __restrict__ out,
                                                 const float* __restrict__ b,
                                                 int total4) {
    int idx = blockIdx.x * blockDim.x + threadIdx.x;
    if (idx >= total4) return;
    int j4 = idx & (F / 4 - 1);
    float4 bv = ((const float4*)b)[j4];
    ((float4*)out)[idx] = bv;
}

__global__ __launch_bounds__(256) void scatter_edges(const int* __restrict__ src,
                                                     const int* __restrict__ dst,
                                                     const float* __restrict__ val,
                                                     const float* __restrict__ Y,
                                                     float* __restrict__ out,
                                                     int n_edges) {
    int e = blockIdx.x * 4 + (threadIdx.x >> 6);
    if (e >= n_edges) return;
    int lane = threadIdx.x & 63;
    int s = src[e];
    int d = dst[e];
    float v = val[e];
    float4 y = *(const float4*)&Y[(size_t)d * F + lane * 4];
    float* o = &out[(size_t)s * F + lane * 4];
    atomicAdd(o + 0, v * y.x);
    atomicAdd(o + 1, v * y.y);
    atomicAdd(o + 2, v * y.z);
    atomicAdd(o + 3, v * y.w);
}

extern "C" void kernel_launch(void* const* d_in, const int* in_sizes, int n_in,
                              void* d_out, int out_size, void* d_ws, size_t ws_size,
                              hipStream_t stream) {
    const float* X        = (const float*)d_in[0];
    const int*   edge_src = (const int*)d_in[1];
    const int*   edge_dst = (const int*)d_in[2];
    const float* edge_val = (const float*)d_in[3];
    const float* W        = (const float*)d_in[4];
    const float* b        = (const float*)d_in[5];
    float*       out      = (float*)d_out;
    const int n_edges     = in_sizes[1];

    char* base = (char*)d_ws;
    const size_t yBytes = (size_t)NNODES * F * sizeof(float);      // 102.4 MB
    float* Y      = (float*)base;
    int2*  pack   = (int2*)(base + yBytes);                        // 8B-aligned
    int*   offs   = (int*)(base + yBytes + (size_t)n_edges * 8);   // NNODES+1 ints
    int*   cursor = offs + (NNODES + 2);
    const size_t needed = yBytes + (size_t)n_edges * 8 + (size_t)(2 * NNODES + 2) * 4;

    dim3 ggrid((NNODES + BM - 1) / BM, F / BN);
    gemm_xwt<<<ggrid, 256, 0, stream>>>(X, W, Y);

    if (ws_size >= needed) {
        // CSR build + gather path (no fp32 atomics)
        zero_int<<<(NNODES + 255) / 256, 256, 0, stream>>>(cursor, NNODES);
        hist_src<<<(n_edges + 255) / 256, 256, 0, stream>>>(edge_src, cursor, n_edges);
        exscan_deg<<<1, 1024, 0, stream>>>(cursor, offs);
        copy_offs<<<(NNODES + 255) / 256, 256, 0, stream>>>(offs, cursor, NNODES);
        reorder_edges<<<(n_edges + 255) / 256, 256, 0, stream>>>(edge_src, edge_dst, edge_val,
                                                                 cursor, pack, n_edges);
        gather_nodes<<<(NNODES + 3) / 4, 256, 0, stream>>>(offs, pack, Y, b, out);
    } else {
        // Fallback: atomic scatter (R1 path)
        int total4 = NNODES * F / 4;
        init_bias<<<(total4 + 255) / 256, 256, 0, stream>>>(out, b, total4);
        int eblocks = (n_edges + 3) / 4;
        scatter_edges<<<eblocks, 256, 0, stream>>>(edge_src, edge_dst, edge_val, Y, out, n_edges);
    }
}

// Round 3
// 868.607 us; speedup vs baseline: 12.5377x; 1.4323x over previous
//
#include <hip/hip_runtime.h>

#define NNODES 100000
#define F 256
#define NB ((NNODES + 1023) / 1024)   // 98 scan blocks

typedef unsigned short u16;
typedef unsigned int   u32;
typedef __attribute__((ext_vector_type(8))) short short8v;  // 8 bf16 (4 VGPRs)
typedef __attribute__((ext_vector_type(4))) float f32x4;

__device__ __forceinline__ u16 f2bf(float f) {
    u32 u = __float_as_uint(f);
    u32 r = u + 0x7FFFu + ((u >> 16) & 1u);   // round-to-nearest-even
    return (u16)(r >> 16);
}
__device__ __forceinline__ float bf2f(u16 h) {
    return __uint_as_float(((u32)h) << 16);
}

// ---------------- cast W -> bf16 ----------------
__global__ __launch_bounds__(256) void cast_w(const float* __restrict__ W,
                                              u16* __restrict__ Wb) {
    int i = blockIdx.x * 256 + threadIdx.x;          // over F*F/4 float4s
    if (i >= F * F / 4) return;
    float4 w = ((const float4*)W)[i];
    ushort4 o;
    o.x = f2bf(w.x); o.y = f2bf(w.y); o.z = f2bf(w.z); o.w = f2bf(w.w);
    ((ushort4*)Wb)[i] = o;
}

// ---------------- GEMM: Yb = bf16( X @ W^T ) via MFMA ----------------
// Block = 4 waves; wave computes 32 rows x 64 cols. Grid (782, 4).
__global__ __launch_bounds__(256) void gemm_mfma(const float* __restrict__ X,
                                                 const u16* __restrict__ Wb,
                                                 u16* __restrict__ Yb) {
    const int wave = threadIdx.x >> 6;
    const int lane = threadIdx.x & 63;
    const int lm   = lane & 15;       // row-in-tile (A) / col-in-tile (B,D)
    const int kg   = lane >> 4;       // k-group 0..3
    const int m0   = blockIdx.x * 128 + wave * 32;
    const int n0   = blockIdx.y * 64;

    f32x4 acc[2][4];
#pragma unroll
    for (int t = 0; t < 2; ++t)
#pragma unroll
        for (int u = 0; u < 4; ++u) acc[t][u] = (f32x4){0.f, 0.f, 0.f, 0.f};

    for (int k0 = 0; k0 < F; k0 += 32) {
        const int kb = k0 + kg * 8;
        short8v aF[2];
#pragma unroll
        for (int t = 0; t < 2; ++t) {
            int row = m0 + t * 16 + lm;
            if (row >= NNODES) row = NNODES - 1;   // clamp; OOB rows not stored
            const float* ap = X + (size_t)row * F + kb;
            float4 x0 = *(const float4*)ap;
            float4 x1 = *(const float4*)(ap + 4);
            short8v a;
            a[0] = (short)f2bf(x0.x); a[1] = (short)f2bf(x0.y);
            a[2] = (short)f2bf(x0.z); a[3] = (short)f2bf(x0.w);
            a[4] = (short)f2bf(x1.x); a[5] = (short)f2bf(x1.y);
            a[6] = (short)f2bf(x1.z); a[7] = (short)f2bf(x1.w);
            aF[t] = a;
        }
        short8v bF[4];
#pragma unroll
        for (int u = 0; u < 4; ++u)
            bF[u] = *(const short8v*)(Wb + (size_t)(n0 + u * 16 + lm) * F + kb);
#pragma unroll
        for (int t = 0; t < 2; ++t)
#pragma unroll
            for (int u = 0; u < 4; ++u)
                acc[t][u] = __builtin_amdgcn_mfma_f32_16x16x32_bf16(aF[t], bF[u], acc[t][u], 0, 0, 0);
    }

    // D layout (16x16x32): col = lane&15, row = (lane>>4)*4 + i
#pragma unroll
    for (int t = 0; t < 2; ++t) {
        int rbase = m0 + t * 16 + kg * 4;
#pragma unroll
        for (int i = 0; i < 4; ++i) {
            int row = rbase + i;
            if (row < NNODES) {
#pragma unroll
                for (int u = 0; u < 4; ++u)
                    Yb[(size_t)row * F + n0 + u * 16 + lm] = f2bf(acc[t][u][i]);
            }
        }
    }
}

// ---------------- CSR build ----------------
__global__ __launch_bounds__(256) void zero_int(int* __restrict__ p, int n) {
    int i = blockIdx.x * blockDim.x + threadIdx.x;
    if (i < n) p[i] = 0;
}

__global__ __launch_bounds__(256) void hist_src(const int* __restrict__ src,
                                                int* __restrict__ deg, int n_edges) {
    int e = blockIdx.x * blockDim.x + threadIdx.x;
    if (e < n_edges) atomicAdd(&deg[src[e]], 1);
}

// Phase 1: per-block exclusive scan (1024 elems/block), emit block sums.
__global__ __launch_bounds__(1024) void scan_block(const int* __restrict__ deg,
                                                   int* __restrict__ offs,
                                                   int* __restrict__ bsum) {
    __shared__ int wsum[16];
    const int tid = threadIdx.x, lane = tid & 63, wid = tid >> 6;
    const int i = blockIdx.x * 1024 + tid;
    int v = (i < NNODES) ? deg[i] : 0;
    int x = v;
#pragma unroll
    for (int off = 1; off < 64; off <<= 1) {
        int t = __shfl_up(x, off, 64);
        if (lane >= off) x += t;
    }
    if (lane == 63) wsum[wid] = x;
    __syncthreads();
    if (wid == 0 && lane < 16) {
        int y = wsum[lane];
        int z = y;
#pragma unroll
        for (int off = 1; off < 16; off <<= 1) {
            int t = __shfl_up(z, off, 64);
            if (lane >= off) z += t;
        }
        wsum[lane] = z - y;
        if (lane == 15) bsum[blockIdx.x] = z;   // block total
    }
    __syncthreads();
    if (i < NNODES) offs[i] = wsum[wid] + (x - v);  // exclusive within block
}

// Phase 2: one block scans the NB block sums (exclusive) + total at [NB].
__global__ __launch_bounds__(128) void scan_sums(int* __restrict__ bsum) {
    __shared__ int s[128];
    int t = threadIdx.x;
    int v = (t < NB) ? bsum[t] : 0;
    s[t] = v;
    __syncthreads();
    for (int off = 1; off < 128; off <<= 1) {
        int x = (t >= off) ? s[t - off] : 0;
        __syncthreads();
        s[t] += x;
        __syncthreads();
    }
    if (t < NB) bsum[t] = s[t] - v;       // exclusive
    if (t == NB - 1) bsum[NB] = s[t];     // grand total
}

// Phase 3: add block base, produce offs + cursor.
__global__ __launch_bounds__(256) void scan_add(int* __restrict__ offs,
                                                const int* __restrict__ bsum,
                                                int* __restrict__ cursor) {
    int i = blockIdx.x * 256 + threadIdx.x;
    if (i < NNODES) {
        int v = offs[i] + bsum[i >> 10];
        offs[i] = v;
        cursor[i] = v;
    }
    if (i == 0) offs[NNODES] = bsum[NB];
}

__global__ __launch_bounds__(256) void reorder_edges(const int* __restrict__ src,
                                                     const int* __restrict__ dst,
                                                     const float* __restrict__ val,
                                                     int* __restrict__ cursor,
                                                     int2* __restrict__ pack,
                                                     int n_edges) {
    int e = blockIdx.x * blockDim.x + threadIdx.x;
    if (e >= n_edges) return;
    int s = src[e];
    int pos = atomicAdd(&cursor[s], 1);
    pack[pos] = make_int2(dst[e], __float_as_int(val[e]));
}

// ---------------- Gather: out[node] = b + sum val * Y[dst]  (bf16 Y) --------
__global__ __launch_bounds__(256) void gather_nodes(const int* __restrict__ offs,
                                                    const int2* __restrict__ pack,
                                                    const u16* __restrict__ Yb,
                                                    const float* __restrict__ b,
                                                    float* __restrict__ out) {
    int node = blockIdx.x * 4 + (threadIdx.x >> 6);
    if (node >= NNODES) return;
    const int lane = threadIdx.x & 63;
    const int beg = offs[node];
    const int end = offs[node + 1];

    float4 acc = ((const float4*)b)[lane];

    int j = beg;
    for (; j + 3 < end; j += 4) {
        int2 p0 = pack[j + 0];
        int2 p1 = pack[j + 1];
        int2 p2 = pack[j + 2];
        int2 p3 = pack[j + 3];
        ushort4 y0 = *(const ushort4*)&Yb[(size_t)p0.x * F + lane * 4];
        ushort4 y1 = *(const ushort4*)&Yb[(size_t)p1.x * F + lane * 4];
        ushort4 y2 = *(const ushort4*)&Yb[(size_t)p2.x * F + lane * 4];
        ushort4 y3 = *(const ushort4*)&Yb[(size_t)p3.x * F + lane * 4];
        float v0 = __int_as_float(p0.y), v1 = __int_as_float(p1.y);
        float v2 = __int_as_float(p2.y), v3 = __int_as_float(p3.y);
        acc.x += v0 * bf2f(y0.x); acc.y += v0 * bf2f(y0.y);
        acc.z += v0 * bf2f(y0.z); acc.w += v0 * bf2f(y0.w);
        acc.x += v1 * bf2f(y1.x); acc.y += v1 * bf2f(y1.y);
        acc.z += v1 * bf2f(y1.z); acc.w += v1 * bf2f(y1.w);
        acc.x += v2 * bf2f(y2.x); acc.y += v2 * bf2f(y2.y);
        acc.z += v2 * bf2f(y2.z); acc.w += v2 * bf2f(y2.w);
        acc.x += v3 * bf2f(y3.x); acc.y += v3 * bf2f(y3.y);
        acc.z += v3 * bf2f(y3.z); acc.w += v3 * bf2f(y3.w);
    }
    for (; j < end; ++j) {
        int2 p = pack[j];
        ushort4 y = *(const ushort4*)&Yb[(size_t)p.x * F + lane * 4];
        float v = __int_as_float(p.y);
        acc.x += v * bf2f(y.x); acc.y += v * bf2f(y.y);
        acc.z += v * bf2f(y.z); acc.w += v * bf2f(y.w);
    }

    *(float4*)&out[(size_t)node * F + lane * 4] = acc;
}

extern "C" void kernel_launch(void* const* d_in, const int* in_sizes, int n_in,
                              void* d_out, int out_size, void* d_ws, size_t ws_size,
                              hipStream_t stream) {
    const float* X        = (const float*)d_in[0];
    const int*   edge_src = (const int*)d_in[1];
    const int*   edge_dst = (const int*)d_in[2];
    const float* edge_val = (const float*)d_in[3];
    const float* W        = (const float*)d_in[4];
    const float* b        = (const float*)d_in[5];
    float*       out      = (float*)d_out;
    const int n_edges     = in_sizes[1];

    // Workspace layout (all sizes 8B-aligned): ~78 MB total
    char* base = (char*)d_ws;
    const size_t ybBytes = (size_t)NNODES * F * sizeof(u16);        // 51.2 MB
    u16*  Yb     = (u16*)base;
    int2* pack   = (int2*)(base + ybBytes);                         // 25.6 MB
    u16*  Wb     = (u16*)(base + ybBytes + (size_t)n_edges * 8);    // 128 KB
    int*  offs   = (int*)((char*)Wb + (size_t)F * F * sizeof(u16));
    int*  cursor = offs + (NNODES + 2);
    int*  bsum   = cursor + NNODES;

    // 1) W -> bf16
    cast_w<<<(F * F / 4 + 255) / 256, 256, 0, stream>>>(W, Wb);

    // 2) Yb = bf16(X @ W^T) via MFMA
    dim3 ggrid((NNODES + 127) / 128, F / 64);
    gemm_mfma<<<ggrid, 256, 0, stream>>>(X, Wb, Yb);

    // 3) CSR build
    zero_int<<<(NNODES + 255) / 256, 256, 0, stream>>>(cursor, NNODES);
    hist_src<<<(n_edges + 255) / 256, 256, 0, stream>>>(edge_src, cursor, n_edges);
    scan_block<<<NB, 1024, 0, stream>>>(cursor, offs, bsum);
    scan_sums<<<1, 128, 0, stream>>>(bsum);
    scan_add<<<(NNODES + 255) / 256, 256, 0, stream>>>(offs, bsum, cursor);
    reorder_edges<<<(n_edges + 255) / 256, 256, 0, stream>>>(edge_src, edge_dst, edge_val,
                                                             cursor, pack, n_edges);

    // 4) Gather + bias
    gather_nodes<<<(NNODES + 3) / 4, 256, 0, stream>>>(offs, pack, Yb, b, out);
}

// Round 4
// 753.758 us; speedup vs baseline: 14.4480x; 1.1524x over previous
//
#include <hip/hip_runtime.h>

#define NNODES 100000
#define F 256
#define NB ((NNODES + 1023) / 1024)     // 98 scan blocks
#define NBKT ((NNODES + 127) / 128)     // 782 buckets of 128 nodes
#define CHUNK 4096                      // edges per bin_edges block

typedef unsigned short u16;
typedef unsigned int   u32;
typedef __attribute__((ext_vector_type(8))) short short8v;  // 8 bf16 (4 VGPRs)
typedef __attribute__((ext_vector_type(4))) float f32x4;

__device__ __forceinline__ u16 f2bf(float f) {
    u32 u = __float_as_uint(f);
    u32 r = u + 0x7FFFu + ((u >> 16) & 1u);   // round-to-nearest-even
    return (u16)(r >> 16);
}
__device__ __forceinline__ float bf2f(u16 h) {
    return __uint_as_float(((u32)h) << 16);
}

// ---------------- cast W -> bf16 ----------------
__global__ __launch_bounds__(256) void cast_w(const float* __restrict__ W,
                                              u16* __restrict__ Wb) {
    int i = blockIdx.x * 256 + threadIdx.x;
    if (i >= F * F / 4) return;
    float4 w = ((const float4*)W)[i];
    ushort4 o;
    o.x = f2bf(w.x); o.y = f2bf(w.y); o.z = f2bf(w.z); o.w = f2bf(w.w);
    ((ushort4*)Wb)[i] = o;
}

// ---------------- GEMM: Yb = bf16( X @ W^T ) via MFMA ----------------
__global__ __launch_bounds__(256) void gemm_mfma(const float* __restrict__ X,
                                                 const u16* __restrict__ Wb,
                                                 u16* __restrict__ Yb) {
    const int wave = threadIdx.x >> 6;
    const int lane = threadIdx.x & 63;
    const int lm   = lane & 15;
    const int kg   = lane >> 4;
    const int m0   = blockIdx.x * 128 + wave * 32;
    const int n0   = blockIdx.y * 64;

    f32x4 acc[2][4];
#pragma unroll
    for (int t = 0; t < 2; ++t)
#pragma unroll
        for (int u = 0; u < 4; ++u) acc[t][u] = (f32x4){0.f, 0.f, 0.f, 0.f};

    for (int k0 = 0; k0 < F; k0 += 32) {
        const int kb = k0 + kg * 8;
        short8v aF[2];
#pragma unroll
        for (int t = 0; t < 2; ++t) {
            int row = m0 + t * 16 + lm;
            if (row >= NNODES) row = NNODES - 1;
            const float* ap = X + (size_t)row * F + kb;
            float4 x0 = *(const float4*)ap;
            float4 x1 = *(const float4*)(ap + 4);
            short8v a;
            a[0] = (short)f2bf(x0.x); a[1] = (short)f2bf(x0.y);
            a[2] = (short)f2bf(x0.z); a[3] = (short)f2bf(x0.w);
            a[4] = (short)f2bf(x1.x); a[5] = (short)f2bf(x1.y);
            a[6] = (short)f2bf(x1.z); a[7] = (short)f2bf(x1.w);
            aF[t] = a;
        }
        short8v bF[4];
#pragma unroll
        for (int u = 0; u < 4; ++u)
            bF[u] = *(const short8v*)(Wb + (size_t)(n0 + u * 16 + lm) * F + kb);
#pragma unroll
        for (int t = 0; t < 2; ++t)
#pragma unroll
            for (int u = 0; u < 4; ++u)
                acc[t][u] = __builtin_amdgcn_mfma_f32_16x16x32_bf16(aF[t], bF[u], acc[t][u], 0, 0, 0);
    }

#pragma unroll
    for (int t = 0; t < 2; ++t) {
        int rbase = m0 + t * 16 + kg * 4;
#pragma unroll
        for (int i = 0; i < 4; ++i) {
            int row = rbase + i;
            if (row < NNODES) {
#pragma unroll
                for (int u = 0; u < 4; ++u)
                    Yb[(size_t)row * F + n0 + u * 16 + lm] = f2bf(acc[t][u][i]);
            }
        }
    }
}

// ---------------- CSR build ----------------
__global__ __launch_bounds__(256) void zero_int(int* __restrict__ p, int n) {
    int i = blockIdx.x * blockDim.x + threadIdx.x;
    if (i < n) p[i] = 0;
}

__global__ __launch_bounds__(256) void hist_src(const int* __restrict__ src,
                                                int* __restrict__ deg, int n_edges) {
    int e = blockIdx.x * blockDim.x + threadIdx.x;
    if (e < n_edges) atomicAdd(&deg[src[e]], 1);
}

__global__ __launch_bounds__(1024) void scan_block(const int* __restrict__ deg,
                                                   int* __restrict__ offs,
                                                   int* __restrict__ bsum) {
    __shared__ int wsum[16];
    const int tid = threadIdx.x, lane = tid & 63, wid = tid >> 6;
    const int i = blockIdx.x * 1024 + tid;
    int v = (i < NNODES) ? deg[i] : 0;
    int x = v;
#pragma unroll
    for (int off = 1; off < 64; off <<= 1) {
        int t = __shfl_up(x, off, 64);
        if (lane >= off) x += t;
    }
    if (lane == 63) wsum[wid] = x;
    __syncthreads();
    if (wid == 0 && lane < 16) {
        int y = wsum[lane];
        int z = y;
#pragma unroll
        for (int off = 1; off < 16; off <<= 1) {
            int t = __shfl_up(z, off, 64);
            if (lane >= off) z += t;
        }
        wsum[lane] = z - y;
        if (lane == 15) bsum[blockIdx.x] = z;
    }
    __syncthreads();
    if (i < NNODES) offs[i] = wsum[wid] + (x - v);
}

__global__ __launch_bounds__(128) void scan_sums(int* __restrict__ bsum) {
    __shared__ int s[128];
    int t = threadIdx.x;
    int v = (t < NB) ? bsum[t] : 0;
    s[t] = v;
    __syncthreads();
    for (int off = 1; off < 128; off <<= 1) {
        int x = (t >= off) ? s[t - off] : 0;
        __syncthreads();
        s[t] += x;
        __syncthreads();
    }
    if (t < NB) bsum[t] = s[t] - v;
    if (t == NB - 1) bsum[NB] = s[t];
}

// add block base; also emit bucket start cursors (bucket = 128 nodes)
__global__ __launch_bounds__(256) void scan_add(int* __restrict__ offs,
                                                const int* __restrict__ bsum,
                                                int* __restrict__ bucket_cur) {
    int i = blockIdx.x * 256 + threadIdx.x;
    if (i < NNODES) {
        int v = offs[i] + bsum[i >> 10];
        offs[i] = v;
        if ((i & 127) == 0) bucket_cur[i >> 7] = v;
    }
    if (i == 0) offs[NNODES] = bsum[NB];
}

// ---------------- Phase A: bin edges into 128-node buckets ----------------
// temp[pos] = ( (src&127)<<20 | dst , val_bits ). Bucket regions coincide with
// final pack regions (bucket_cur starts at offs[b*128]).
__global__ __launch_bounds__(256) void bin_edges(const int* __restrict__ src,
                                                 const int* __restrict__ dst,
                                                 const float* __restrict__ val,
                                                 int* __restrict__ bucket_cur,
                                                 int2* __restrict__ temp,
                                                 int n_edges) {
    __shared__ int hist[NBKT];
    __shared__ int base[NBKT];
    const int e0 = blockIdx.x * CHUNK;
    for (int i = threadIdx.x; i < NBKT; i += 256) hist[i] = 0;
    __syncthreads();

    int s[16], lp[16];
#pragma unroll
    for (int k = 0; k < 16; ++k) {
        int e = e0 + k * 256 + threadIdx.x;
        s[k] = (e < n_edges) ? src[e] : -1;
        if (s[k] >= 0) lp[k] = atomicAdd(&hist[s[k] >> 7], 1);
    }
    __syncthreads();
    for (int i = threadIdx.x; i < NBKT; i += 256) {
        int c = hist[i];
        base[i] = c ? atomicAdd(&bucket_cur[i], c) : 0;
    }
    __syncthreads();
#pragma unroll
    for (int k = 0; k < 16; ++k) {
        int e = e0 + k * 256 + threadIdx.x;
        if (s[k] >= 0) {
            int pos = base[s[k] >> 7] + lp[k];
            temp[pos] = make_int2(((s[k] & 127) << 20) | dst[e], __float_as_int(val[e]));
        }
    }
}

// ---------------- Phase B: sort each bucket by node into pack ----------------
__global__ __launch_bounds__(256) void sort_bucket(const int* __restrict__ offs,
                                                   const int2* __restrict__ temp,
                                                   int2* __restrict__ pack) {
    __shared__ int cur[128];
    const int b = blockIdx.x;
    const int n0 = b * 128;
    for (int i = threadIdx.x; i < 128; i += 256) {
        int node = n0 + i;
        cur[i] = (node < NNODES) ? offs[node] : 0;
    }
    __syncthreads();
    const int beg = offs[n0];
    const int nend = (n0 + 128 < NNODES) ? n0 + 128 : NNODES;
    const int end = offs[nend];
    for (int j = beg + threadIdx.x; j < end; j += 256) {
        int2 p = temp[j];
        int loc = p.x >> 20;
        int pos = atomicAdd(&cur[loc], 1);
        pack[pos] = make_int2(p.x & 0xFFFFF, p.y);
    }
}

// ---------------- Gather: out[node] = b + sum val * Y[dst]  (bf16 Y) --------
__global__ __launch_bounds__(256) void gather_nodes(const int* __restrict__ offs,
                                                    const int2* __restrict__ pack,
                                                    const u16* __restrict__ Yb,
                                                    const float* __restrict__ b,
                                                    float* __restrict__ out) {
    int node = blockIdx.x * 4 + (threadIdx.x >> 6);
    if (node >= NNODES) return;
    const int lane = threadIdx.x & 63;
    const int beg = offs[node];
    const int end = offs[node + 1];

    float4 acc = ((const float4*)b)[lane];

    int j = beg;
    for (; j + 3 < end; j += 4) {
        int2 p0 = pack[j + 0];
        int2 p1 = pack[j + 1];
        int2 p2 = pack[j + 2];
        int2 p3 = pack[j + 3];
        ushort4 y0 = *(const ushort4*)&Yb[(size_t)p0.x * F + lane * 4];
        ushort4 y1 = *(const ushort4*)&Yb[(size_t)p1.x * F + lane * 4];
        ushort4 y2 = *(const ushort4*)&Yb[(size_t)p2.x * F + lane * 4];
        ushort4 y3 = *(const ushort4*)&Yb[(size_t)p3.x * F + lane * 4];
        float v0 = __int_as_float(p0.y), v1 = __int_as_float(p1.y);
        float v2 = __int_as_float(p2.y), v3 = __int_as_float(p3.y);
        acc.x += v0 * bf2f(y0.x); acc.y += v0 * bf2f(y0.y);
        acc.z += v0 * bf2f(y0.z); acc.w += v0 * bf2f(y0.w);
        acc.x += v1 * bf2f(y1.x); acc.y += v1 * bf2f(y1.y);
        acc.z += v1 * bf2f(y1.z); acc.w += v1 * bf2f(y1.w);
        acc.x += v2 * bf2f(y2.x); acc.y += v2 * bf2f(y2.y);
        acc.z += v2 * bf2f(y2.z); acc.w += v2 * bf2f(y2.w);
        acc.x += v3 * bf2f(y3.x); acc.y += v3 * bf2f(y3.y);
        acc.z += v3 * bf2f(y3.z); acc.w += v3 * bf2f(y3.w);
    }
    for (; j < end; ++j) {
        int2 p = pack[j];
        ushort4 y = *(const ushort4*)&Yb[(size_t)p.x * F + lane * 4];
        float v = __int_as_float(p.y);
        acc.x += v * bf2f(y.x); acc.y += v * bf2f(y.y);
        acc.z += v * bf2f(y.z); acc.w += v * bf2f(y.w);
    }

    *(float4*)&out[(size_t)node * F + lane * 4] = acc;
}

extern "C" void kernel_launch(void* const* d_in, const int* in_sizes, int n_in,
                              void* d_out, int out_size, void* d_ws, size_t ws_size,
                              hipStream_t stream) {
    const float* X        = (const float*)d_in[0];
    const int*   edge_src = (const int*)d_in[1];
    const int*   edge_dst = (const int*)d_in[2];
    const float* edge_val = (const float*)d_in[3];
    const float* W        = (const float*)d_in[4];
    const float* b        = (const float*)d_in[5];
    float*       out      = (float*)d_out;
    const int n_edges     = in_sizes[1];

    // Workspace layout (~103 MB total; harness provides >= 128 MB per R2)
    char* base = (char*)d_ws;
    const size_t ybBytes = (size_t)NNODES * F * sizeof(u16);        // 51.2 MB
    u16*  Yb     = (u16*)base;
    int2* pack   = (int2*)(base + ybBytes);                         // 25.6 MB
    int2* temp   = pack + n_edges;                                  // 25.6 MB
    u16*  Wb     = (u16*)(temp + n_edges);                          // 128 KB
    int*  offs   = (int*)((char*)Wb + (size_t)F * F * sizeof(u16)); // NNODES+2
    int*  deg    = offs + (NNODES + 2);                             // NNODES
    int*  bsum   = deg + NNODES;                                    // NB+1
    int*  bucket_cur = bsum + (NB + 2);                             // NBKT

    // 1) W -> bf16
    cast_w<<<(F * F / 4 + 255) / 256, 256, 0, stream>>>(W, Wb);

    // 2) Yb = bf16(X @ W^T) via MFMA
    dim3 ggrid((NNODES + 127) / 128, F / 64);
    gemm_mfma<<<ggrid, 256, 0, stream>>>(X, Wb, Yb);

    // 3) degree histogram + scan (offs), bucket cursors
    zero_int<<<(NNODES + 255) / 256, 256, 0, stream>>>(deg, NNODES);
    hist_src<<<(n_edges + 255) / 256, 256, 0, stream>>>(edge_src, deg, n_edges);
    scan_block<<<NB, 1024, 0, stream>>>(deg, offs, bsum);
    scan_sums<<<1, 128, 0, stream>>>(bsum);
    scan_add<<<(NNODES + 255) / 256, 256, 0, stream>>>(offs, bsum, bucket_cur);

    // 4) two-phase binned counting sort of edges
    bin_edges<<<(n_edges + CHUNK - 1) / CHUNK, 256, 0, stream>>>(edge_src, edge_dst, edge_val,
                                                                 bucket_cur, temp, n_edges);
    sort_bucket<<<NBKT, 256, 0, stream>>>(offs, temp, pack);

    // 5) Gather + bias
    gather_nodes<<<(NNODES + 3) / 4, 256, 0, stream>>>(offs, pack, Yb, b, out);
}

// Round 5
// 750.306 us; speedup vs baseline: 14.5145x; 1.0046x over previous
//
#include <hip/hip_runtime.h>

#define NNODES 100000
#define F 256
#define NB ((NNODES + 1023) / 1024)     // 98 scan blocks
#define NBKT ((NNODES + 127) / 128)     // 782 buckets of 128 nodes
#define CHUNK 4096                      // edges per bin_edges block

typedef unsigned short u16;
typedef unsigned int   u32;
typedef __attribute__((ext_vector_type(8))) short short8v;  // 8 bf16 (4 VGPRs)
typedef __attribute__((ext_vector_type(4))) float f32x4;

__device__ __forceinline__ u16 f2bf(float f) {
    u32 u = __float_as_uint(f);
    u32 r = u + 0x7FFFu + ((u >> 16) & 1u);   // round-to-nearest-even
    return (u16)(r >> 16);
}
__device__ __forceinline__ float bf2f(u16 h) {
    return __uint_as_float(((u32)h) << 16);
}

// ---------------- cast W -> bf16 ----------------
__global__ __launch_bounds__(256) void cast_w(const float* __restrict__ W,
                                              u16* __restrict__ Wb) {
    int i = blockIdx.x * 256 + threadIdx.x;
    if (i >= F * F / 4) return;
    float4 w = ((const float4*)W)[i];
    ushort4 o;
    o.x = f2bf(w.x); o.y = f2bf(w.y); o.z = f2bf(w.z); o.w = f2bf(w.w);
    ((ushort4*)Wb)[i] = o;
}

// ---------------- cast X -> bf16 (streaming) ----------------
__global__ __launch_bounds__(256) void cast_x(const float* __restrict__ X,
                                              u16* __restrict__ Xb, int total4) {
    int i = blockIdx.x * 256 + threadIdx.x;
    if (i >= total4) return;
    float4 x = ((const float4*)X)[i];
    ushort4 o;
    o.x = f2bf(x.x); o.y = f2bf(x.y); o.z = f2bf(x.z); o.w = f2bf(x.w);
    ((ushort4*)Xb)[i] = o;
}

// ---------------- GEMM: Yb = bf16( Xb @ Wb^T ) via MFMA ----------------
// Block = 4 waves; wave computes 32 rows x 64 cols. Grid (782, 4).
__global__ __launch_bounds__(256) void gemm_mfma(const u16* __restrict__ Xb,
                                                 const u16* __restrict__ Wb,
                                                 u16* __restrict__ Yb) {
    const int wave = threadIdx.x >> 6;
    const int lane = threadIdx.x & 63;
    const int lm   = lane & 15;
    const int kg   = lane >> 4;
    const int m0   = blockIdx.x * 128 + wave * 32;
    const int n0   = blockIdx.y * 64;

    f32x4 acc[2][4];
#pragma unroll
    for (int t = 0; t < 2; ++t)
#pragma unroll
        for (int u = 0; u < 4; ++u) acc[t][u] = (f32x4){0.f, 0.f, 0.f, 0.f};

    int rowA[2];
#pragma unroll
    for (int t = 0; t < 2; ++t) {
        int row = m0 + t * 16 + lm;
        rowA[t] = (row < NNODES) ? row : NNODES - 1;   // clamp; OOB rows not stored
    }

    for (int k0 = 0; k0 < F; k0 += 32) {
        const int kb = k0 + kg * 8;
        short8v aF[2];
#pragma unroll
        for (int t = 0; t < 2; ++t)
            aF[t] = *(const short8v*)(Xb + (size_t)rowA[t] * F + kb);
        short8v bF[4];
#pragma unroll
        for (int u = 0; u < 4; ++u)
            bF[u] = *(const short8v*)(Wb + (size_t)(n0 + u * 16 + lm) * F + kb);
#pragma unroll
        for (int t = 0; t < 2; ++t)
#pragma unroll
            for (int u = 0; u < 4; ++u)
                acc[t][u] = __builtin_amdgcn_mfma_f32_16x16x32_bf16(aF[t], bF[u], acc[t][u], 0, 0, 0);
    }

    // D layout (16x16x32): col = lane&15, row = (lane>>4)*4 + i
#pragma unroll
    for (int t = 0; t < 2; ++t) {
        int rbase = m0 + t * 16 + kg * 4;
#pragma unroll
        for (int i = 0; i < 4; ++i) {
            int row = rbase + i;
            if (row < NNODES) {
#pragma unroll
                for (int u = 0; u < 4; ++u)
                    Yb[(size_t)row * F + n0 + u * 16 + lm] = f2bf(acc[t][u][i]);
            }
        }
    }
}

// ---------------- CSR build ----------------
__global__ __launch_bounds__(256) void zero_int(int* __restrict__ p, int n) {
    int i = blockIdx.x * blockDim.x + threadIdx.x;
    if (i < n) p[i] = 0;
}

__global__ __launch_bounds__(256) void hist_src(const int* __restrict__ src,
                                                int* __restrict__ deg, int n_edges) {
    int e = blockIdx.x * blockDim.x + threadIdx.x;
    if (e < n_edges) atomicAdd(&deg[src[e]], 1);
}

__global__ __launch_bounds__(1024) void scan_block(const int* __restrict__ deg,
                                                   int* __restrict__ offs,
                                                   int* __restrict__ bsum) {
    __shared__ int wsum[16];
    const int tid = threadIdx.x, lane = tid & 63, wid = tid >> 6;
    const int i = blockIdx.x * 1024 + tid;
    int v = (i < NNODES) ? deg[i] : 0;
    int x = v;
#pragma unroll
    for (int off = 1; off < 64; off <<= 1) {
        int t = __shfl_up(x, off, 64);
        if (lane >= off) x += t;
    }
    if (lane == 63) wsum[wid] = x;
    __syncthreads();
    if (wid == 0 && lane < 16) {
        int y = wsum[lane];
        int z = y;
#pragma unroll
        for (int off = 1; off < 16; off <<= 1) {
            int t = __shfl_up(z, off, 64);
            if (lane >= off) z += t;
        }
        wsum[lane] = z - y;
        if (lane == 15) bsum[blockIdx.x] = z;
    }
    __syncthreads();
    if (i < NNODES) offs[i] = wsum[wid] + (x - v);
}

__global__ __launch_bounds__(128) void scan_sums(int* __restrict__ bsum) {
    __shared__ int s[128];
    int t = threadIdx.x;
    int v = (t < NB) ? bsum[t] : 0;
    s[t] = v;
    __syncthreads();
    for (int off = 1; off < 128; off <<= 1) {
        int x = (t >= off) ? s[t - off] : 0;
        __syncthreads();
        s[t] += x;
        __syncthreads();
    }
    if (t < NB) bsum[t] = s[t] - v;
    if (t == NB - 1) bsum[NB] = s[t];
}

__global__ __launch_bounds__(256) void scan_add(int* __restrict__ offs,
                                                const int* __restrict__ bsum,
                                                int* __restrict__ bucket_cur) {
    int i = blockIdx.x * 256 + threadIdx.x;
    if (i < NNODES) {
        int v = offs[i] + bsum[i >> 10];
        offs[i] = v;
        if ((i & 127) == 0) bucket_cur[i >> 7] = v;
    }
    if (i == 0) offs[NNODES] = bsum[NB];
}

// ---------------- Phase A: bin edges into 128-node buckets ----------------
__global__ __launch_bounds__(256) void bin_edges(const int* __restrict__ src,
                                                 const int* __restrict__ dst,
                                                 const float* __restrict__ val,
                                                 int* __restrict__ bucket_cur,
                                                 int2* __restrict__ temp,
                                                 int n_edges) {
    __shared__ int hist[NBKT];
    __shared__ int base[NBKT];
    const int e0 = blockIdx.x * CHUNK;
    for (int i = threadIdx.x; i < NBKT; i += 256) hist[i] = 0;
    __syncthreads();

    int s[16], lp[16];
#pragma unroll
    for (int k = 0; k < 16; ++k) {
        int e = e0 + k * 256 + threadIdx.x;
        s[k] = (e < n_edges) ? src[e] : -1;
        if (s[k] >= 0) lp[k] = atomicAdd(&hist[s[k] >> 7], 1);
    }
    __syncthreads();
    for (int i = threadIdx.x; i < NBKT; i += 256) {
        int c = hist[i];
        base[i] = c ? atomicAdd(&bucket_cur[i], c) : 0;
    }
    __syncthreads();
#pragma unroll
    for (int k = 0; k < 16; ++k) {
        int e = e0 + k * 256 + threadIdx.x;
        if (s[k] >= 0) {
            int pos = base[s[k] >> 7] + lp[k];
            temp[pos] = make_int2(((s[k] & 127) << 20) | dst[e], __float_as_int(val[e]));
        }
    }
}

// ---------------- Phase B: sort each bucket by node into pack ----------------
__global__ __launch_bounds__(256) void sort_bucket(const int* __restrict__ offs,
                                                   const int2* __restrict__ temp,
                                                   int2* __restrict__ pack) {
    __shared__ int cur[128];
    const int b = blockIdx.x;
    const int n0 = b * 128;
    for (int i = threadIdx.x; i < 128; i += 256) {
        int node = n0 + i;
        cur[i] = (node < NNODES) ? offs[node] : 0;
    }
    __syncthreads();
    const int beg = offs[n0];
    const int nend = (n0 + 128 < NNODES) ? n0 + 128 : NNODES;
    const int end = offs[nend];
    for (int j = beg + threadIdx.x; j < end; j += 256) {
        int2 p = temp[j];
        int loc = p.x >> 20;
        int pos = atomicAdd(&cur[loc], 1);
        pack[pos] = make_int2(p.x & 0xFFFFF, p.y);
    }
}

// ---------------- Gather: out[node] = b + sum val * Y[dst]  (bf16 Y) --------
#define GACC(P, Y) do {                                        \
    float v_ = __int_as_float((P).y);                          \
    acc.x += v_ * bf2f((Y).x); acc.y += v_ * bf2f((Y).y);      \
    acc.z += v_ * bf2f((Y).z); acc.w += v_ * bf2f((Y).w);      \
} while (0)

__global__ __launch_bounds__(256) void gather_nodes(const int* __restrict__ offs,
                                                    const int2* __restrict__ pack,
                                                    const u16* __restrict__ Yb,
                                                    const float* __restrict__ b,
                                                    float* __restrict__ out) {
    int node = blockIdx.x * 4 + (threadIdx.x >> 6);
    if (node >= NNODES) return;
    const int lane = threadIdx.x & 63;
    const int beg = offs[node];
    const int end = offs[node + 1];

    float4 acc = ((const float4*)b)[lane];

    int j = beg;
    for (; j + 7 < end; j += 8) {
        int2 p[8];
        ushort4 y[8];
#pragma unroll
        for (int q = 0; q < 8; ++q) p[q] = pack[j + q];
#pragma unroll
        for (int q = 0; q < 8; ++q)
            y[q] = *(const ushort4*)&Yb[(size_t)p[q].x * F + lane * 4];
#pragma unroll
        for (int q = 0; q < 8; ++q) GACC(p[q], y[q]);
    }
    for (; j < end; ++j) {
        int2 p = pack[j];
        ushort4 y = *(const ushort4*)&Yb[(size_t)p.x * F + lane * 4];
        GACC(p, y);
    }

    // Non-temporal: out is write-once streaming; keep Yb resident in LLC.
    __builtin_nontemporal_store(*(f32x4*)&acc, (f32x4*)&out[(size_t)node * F + lane * 4]);
}

extern "C" void kernel_launch(void* const* d_in, const int* in_sizes, int n_in,
                              void* d_out, int out_size, void* d_ws, size_t ws_size,
                              hipStream_t stream) {
    const float* X        = (const float*)d_in[0];
    const int*   edge_src = (const int*)d_in[1];
    const int*   edge_dst = (const int*)d_in[2];
    const float* edge_val = (const float*)d_in[3];
    const float* W        = (const float*)d_in[4];
    const float* b        = (const float*)d_in[5];
    float*       out      = (float*)d_out;
    const int n_edges     = in_sizes[1];

    // Workspace (~103.3 MB): Xb overlays pack+temp (Xb dead before bin_edges).
    char* base = (char*)d_ws;
    const size_t ybBytes = (size_t)NNODES * F * sizeof(u16);        // 51.2 MB
    u16*  Yb     = (u16*)base;
    int2* pack   = (int2*)(base + ybBytes);                         // 25.6 MB
    int2* temp   = pack + n_edges;                                  // 25.6 MB
    u16*  Xb     = (u16*)pack;                                      // 51.2 MB overlay
    u16*  Wb     = (u16*)(temp + n_edges);                          // 128 KB
    int*  offs   = (int*)((char*)Wb + (size_t)F * F * sizeof(u16)); // NNODES+2
    int*  deg    = offs + (NNODES + 2);                             // NNODES
    int*  bsum   = deg + NNODES;                                    // NB+1
    int*  bucket_cur = bsum + (NB + 2);                             // NBKT

    // 1) casts
    cast_w<<<(F * F / 4 + 255) / 256, 256, 0, stream>>>(W, Wb);
    int xt4 = NNODES * F / 4;
    cast_x<<<(xt4 + 255) / 256, 256, 0, stream>>>(X, Xb, xt4);

    // 2) Yb = bf16(Xb @ Wb^T) via MFMA
    dim3 ggrid((NNODES + 127) / 128, F / 64);
    gemm_mfma<<<ggrid, 256, 0, stream>>>(Xb, Wb, Yb);

    // 3) degree histogram + scan (offs), bucket cursors
    zero_int<<<(NNODES + 255) / 256, 256, 0, stream>>>(deg, NNODES);
    hist_src<<<(n_edges + 255) / 256, 256, 0, stream>>>(edge_src, deg, n_edges);
    scan_block<<<NB, 1024, 0, stream>>>(deg, offs, bsum);
    scan_sums<<<1, 128, 0, stream>>>(bsum);
    scan_add<<<(NNODES + 255) / 256, 256, 0, stream>>>(offs, bsum, bucket_cur);

    // 4) two-phase binned counting sort (temp then pack; Xb dead by now)
    bin_edges<<<(n_edges + CHUNK - 1) / CHUNK, 256, 0, stream>>>(edge_src, edge_dst, edge_val,
                                                                 bucket_cur, temp, n_edges);
    sort_bucket<<<NBKT, 256, 0, stream>>>(offs, temp, pack);

    // 5) Gather + bias
    gather_nodes<<<(NNODES + 3) / 4, 256, 0, stream>>>(offs, pack, Yb, b, out);
}

// Round 6
// 605.068 us; speedup vs baseline: 17.9985x; 1.2400x over previous
//
#include <hip/hip_runtime.h>

#define NNODES 100000
#define F 256
#define NBKT ((NNODES + 127) / 128)    // 782 buckets of 128 src nodes
#define BKT_CAP 5120                   // mean 4092, +16 sigma; P(overflow) ~ 1e-13
#define CHUNK_A 8192                   // edges per bin_edges block

typedef unsigned short u16;
typedef unsigned int   u32;
typedef __attribute__((ext_vector_type(8))) short short8v;      // 8 bf16
typedef __attribute__((ext_vector_type(8))) unsigned short ushort8; // 8 bf16 bits
typedef __attribute__((ext_vector_type(4))) float f32x4;

__device__ __forceinline__ u16 f2bf(float f) {
    u32 u = __float_as_uint(f);
    u32 r = u + 0x7FFFu + ((u >> 16) & 1u);   // round-to-nearest-even
    return (u16)(r >> 16);
}
__device__ __forceinline__ float bf2f(u16 h) {
    return __uint_as_float(((u32)h) << 16);
}

// ---------------- cast W -> bf16 ----------------
__global__ __launch_bounds__(256) void cast_w(const float* __restrict__ W,
                                              u16* __restrict__ Wb) {
    int i = blockIdx.x * 256 + threadIdx.x;
    if (i >= F * F / 4) return;
    float4 w = ((const float4*)W)[i];
    ushort4 o;
    o.x = f2bf(w.x); o.y = f2bf(w.y); o.z = f2bf(w.z); o.w = f2bf(w.w);
    ((ushort4*)Wb)[i] = o;
}

// ---------------- cast X -> bf16 (streaming) ----------------
__global__ __launch_bounds__(256) void cast_x(const float* __restrict__ X,
                                              u16* __restrict__ Xb, int total4) {
    int i = blockIdx.x * 256 + threadIdx.x;
    if (i >= total4) return;
    float4 x = ((const float4*)X)[i];
    ushort4 o;
    o.x = f2bf(x.x); o.y = f2bf(x.y); o.z = f2bf(x.z); o.w = f2bf(x.w);
    ((ushort4*)Xb)[i] = o;
}

// ---------------- GEMM: Yb = bf16( Xb @ Wb^T ) via MFMA ----------------
__global__ __launch_bounds__(256) void gemm_mfma(const u16* __restrict__ Xb,
                                                 const u16* __restrict__ Wb,
                                                 u16* __restrict__ Yb) {
    const int wave = threadIdx.x >> 6;
    const int lane = threadIdx.x & 63;
    const int lm   = lane & 15;
    const int kg   = lane >> 4;
    const int m0   = blockIdx.x * 128 + wave * 32;
    const int n0   = blockIdx.y * 64;

    f32x4 acc[2][4];
#pragma unroll
    for (int t = 0; t < 2; ++t)
#pragma unroll
        for (int u = 0; u < 4; ++u) acc[t][u] = (f32x4){0.f, 0.f, 0.f, 0.f};

    int rowA[2];
#pragma unroll
    for (int t = 0; t < 2; ++t) {
        int row = m0 + t * 16 + lm;
        rowA[t] = (row < NNODES) ? row : NNODES - 1;
    }

    for (int k0 = 0; k0 < F; k0 += 32) {
        const int kb = k0 + kg * 8;
        short8v aF[2];
#pragma unroll
        for (int t = 0; t < 2; ++t)
            aF[t] = *(const short8v*)(Xb + (size_t)rowA[t] * F + kb);
        short8v bF[4];
#pragma unroll
        for (int u = 0; u < 4; ++u)
            bF[u] = *(const short8v*)(Wb + (size_t)(n0 + u * 16 + lm) * F + kb);
#pragma unroll
        for (int t = 0; t < 2; ++t)
#pragma unroll
            for (int u = 0; u < 4; ++u)
                acc[t][u] = __builtin_amdgcn_mfma_f32_16x16x32_bf16(aF[t], bF[u], acc[t][u], 0, 0, 0);
    }

    // D layout (16x16x32): col = lane&15, row = (lane>>4)*4 + i
#pragma unroll
    for (int t = 0; t < 2; ++t) {
        int rbase = m0 + t * 16 + kg * 4;
#pragma unroll
        for (int i = 0; i < 4; ++i) {
            int row = rbase + i;
            if (row < NNODES) {
#pragma unroll
                for (int u = 0; u < 4; ++u)
                    Yb[(size_t)row * F + n0 + u * 16 + lm] = f2bf(acc[t][u][i]);
            }
        }
    }
}

// ---------------- init bucket cursors ----------------
__global__ __launch_bounds__(256) void init_cur(int* __restrict__ cur) {
    int i = blockIdx.x * 256 + threadIdx.x;
    if (i < NBKT) cur[i] = i * BKT_CAP;
}

// ---------------- Phase A: bin edges into 128-node buckets ----------------
// temp[pos] = ( (src&127)<<20 | dst , val_bits ), bucket-strided regions.
__global__ __launch_bounds__(256) void bin_edges(const int* __restrict__ src,
                                                 const int* __restrict__ dst,
                                                 const float* __restrict__ val,
                                                 int* __restrict__ cur,
                                                 int2* __restrict__ temp,
                                                 int n_edges) {
    __shared__ int hist[NBKT];
    __shared__ int bas[NBKT];
    const int e0 = blockIdx.x * CHUNK_A;
    for (int i = threadIdx.x; i < NBKT; i += 256) hist[i] = 0;
    __syncthreads();

    int lp[32];
#pragma unroll
    for (int k = 0; k < 32; ++k) {
        int e = e0 + k * 256 + threadIdx.x;
        if (e < n_edges) lp[k] = atomicAdd(&hist[src[e] >> 7], 1);
    }
    __syncthreads();
    for (int i = threadIdx.x; i < NBKT; i += 256) {
        int c = hist[i];
        bas[i] = c ? atomicAdd(&cur[i], c) : 0;
    }
    __syncthreads();
#pragma unroll
    for (int k = 0; k < 32; ++k) {
        int e = e0 + k * 256 + threadIdx.x;
        if (e < n_edges) {
            int s = src[e];
            int pos = bas[s >> 7] + lp[k];
            temp[pos] = make_int2(((s & 127) << 20) | dst[e], __float_as_int(val[e]));
        }
    }
}

// ---------------- Phase B: per-bucket node sort + nodeseg emit ----------------
__global__ __launch_bounds__(256) void sort_bucket(const int* __restrict__ cur,
                                                   const int2* __restrict__ temp,
                                                   int2* __restrict__ pack,
                                                   int2* __restrict__ nodeseg) {
    __shared__ int h[128];
    __shared__ int curl[128];
    const int b = blockIdx.x;
    const int base = b * BKT_CAP;
    const int cnt = cur[b] - base;
    const int tid = threadIdx.x;

    if (tid < 128) h[tid] = 0;
    __syncthreads();
    for (int j = tid; j < cnt; j += 256)
        atomicAdd(&h[temp[base + j].x >> 20], 1);
    __syncthreads();
    // inclusive scan over 128 entries
    for (int off = 1; off < 128; off <<= 1) {
        int x = 0;
        if (tid < 128 && tid >= off) x = h[tid - off];
        __syncthreads();
        if (tid < 128) h[tid] += x;
        __syncthreads();
    }
    if (tid < 128) {
        int incl = h[tid];
        int prev = tid ? h[tid - 1] : 0;
        curl[tid] = base + prev;
        int node = b * 128 + tid;
        if (node < NNODES) nodeseg[node] = make_int2(base + prev, base + incl);
    }
    __syncthreads();
    for (int j = tid; j < cnt; j += 256) {
        int2 p = temp[base + j];
        int loc = p.x >> 20;
        int pos = atomicAdd(&curl[loc], 1);
        pack[pos] = make_int2(p.x & 0xFFFFF, p.y);
    }
}

// ---------------- Gather: out[node] = b + sum val * Y[dst]  (bf16 Y) --------
// One wave per node. Lanes 0-31 handle even edges, 32-63 odd edges; each lane
// owns 8 feats (16 B loads). shfl_xor(32) combines the two halves at the end.
__global__ __launch_bounds__(256) void gather_nodes(const int2* __restrict__ nodeseg,
                                                    const int2* __restrict__ pack,
                                                    const u16* __restrict__ Yb,
                                                    const float* __restrict__ bias,
                                                    float* __restrict__ out) {
    int node = blockIdx.x * 4 + (threadIdx.x >> 6);
    if (node >= NNODES) return;
    const int lane = threadIdx.x & 63;
    const int half = lane >> 5;
    const int l5   = lane & 31;

    int2 seg = nodeseg[node];
    const int beg = seg.x, end = seg.y;

    float acc[8];
#pragma unroll
    for (int i = 0; i < 8; ++i) acc[i] = 0.f;

    for (int j = beg; j < end; j += 8) {     // 4 pairs = 8 edges per iter
        int dsts[4];
        float v[4];
        ushort8 y[4];
#pragma unroll
        for (int q = 0; q < 4; ++q) {
            int idx = j + 2 * q + half;
            int safe = idx < end ? idx : end - 1;
            long long raw = __builtin_nontemporal_load((const long long*)&pack[safe]);
            dsts[q] = (int)(raw & 0xFFFFFFFFll);
            v[q] = (idx < end) ? __int_as_float((int)(raw >> 32)) : 0.f;
        }
#pragma unroll
        for (int q = 0; q < 4; ++q)
            y[q] = *(const ushort8*)(Yb + (size_t)dsts[q] * F + l5 * 8);
#pragma unroll
        for (int q = 0; q < 4; ++q)
#pragma unroll
            for (int i = 0; i < 8; ++i)
                acc[i] += v[q] * bf2f(y[q][i]);
    }

    // combine halves
#pragma unroll
    for (int i = 0; i < 8; ++i) acc[i] += __shfl_xor(acc[i], 32);

    // bias + store: lane writes feats [l5*8 + half*4 .. +3]
    const int col = l5 * 8 + half * 4;
    float4 bv = *(const float4*)&bias[col];
    f32x4 o;
    o[0] = acc[half * 4 + 0] + bv.x;
    o[1] = acc[half * 4 + 1] + bv.y;
    o[2] = acc[half * 4 + 2] + bv.z;
    o[3] = acc[half * 4 + 3] + bv.w;
    __builtin_nontemporal_store(o, (f32x4*)&out[(size_t)node * F + col]);
}

extern "C" void kernel_launch(void* const* d_in, const int* in_sizes, int n_in,
                              void* d_out, int out_size, void* d_ws, size_t ws_size,
                              hipStream_t stream) {
    const float* X        = (const float*)d_in[0];
    const int*   edge_src = (const int*)d_in[1];
    const int*   edge_dst = (const int*)d_in[2];
    const float* edge_val = (const float*)d_in[3];
    const float* W        = (const float*)d_in[4];
    const float* b        = (const float*)d_in[5];
    float*       out      = (float*)d_out;
    const int n_edges     = in_sizes[1];

    // Workspace (~116.2 MB). Xb (51.2 MB) overlays pack+temp (64.1 MB):
    // Xb is dead after gemm; temp/pack are written only after gemm.
    char* base = (char*)d_ws;
    const size_t ybBytes   = (size_t)NNODES * F * sizeof(u16);        // 51.2 MB
    const size_t packBytes = (size_t)NBKT * BKT_CAP * sizeof(int2);   // 32.03 MB
    u16*  Yb      = (u16*)base;
    int2* pack    = (int2*)(base + ybBytes);
    int2* temp    = (int2*)(base + ybBytes + packBytes);
    u16*  Xb      = (u16*)pack;                                       // overlay
    u16*  Wb      = (u16*)(base + ybBytes + 2 * packBytes);
    int2* nodeseg = (int2*)((char*)Wb + (size_t)F * F * sizeof(u16));
    int*  cur     = (int*)(nodeseg + NNODES);

    // 1) casts
    cast_w<<<(F * F / 4 + 255) / 256, 256, 0, stream>>>(W, Wb);
    int xt4 = NNODES * F / 4;
    cast_x<<<(xt4 + 255) / 256, 256, 0, stream>>>(X, Xb, xt4);

    // 2) Yb = bf16(Xb @ Wb^T) via MFMA
    dim3 ggrid((NNODES + 127) / 128, F / 64);
    gemm_mfma<<<ggrid, 256, 0, stream>>>(Xb, Wb, Yb);

    // 3) bucket cursors + two-phase binned counting sort (no global scan)
    init_cur<<<(NBKT + 255) / 256, 256, 0, stream>>>(cur);
    bin_edges<<<(n_edges + CHUNK_A - 1) / CHUNK_A, 256, 0, stream>>>(edge_src, edge_dst, edge_val,
                                                                     cur, temp, n_edges);
    sort_bucket<<<NBKT, 256, 0, stream>>>(cur, temp, pack, nodeseg);

    // 4) Gather + bias
    gather_nodes<<<(NNODES + 3) / 4, 256, 0, stream>>>(nodeseg, pack, Yb, b, out);
}